// Round 10
// baseline (691.919 us; speedup 1.0000x reference)
//
#include <hip/hip_runtime.h>
#include <stdint.h>

// DecodeDetections (SSD): decode + per-class top-512 + greedy NMS + per-batch top-200.
// B=32, N=8732, C=80 foreground classes, K=512 candidates, NMS cap 400, out top-200.

#define BATCH   32
#define NBOX    8732
#define NCH     93
#define NCLS    80
#define KSEL    512
#define NMSMAX  400
#define RPC     200      // rows materialized per class (top-200 of batch can't reach deeper;
                         // NMS may stop at 200 kept: row r>=200 has >=200 same-class rows above it)
#define TOPK    200
#define CONF    0.01f
#define IOU_T   0.45f
#define NPT     35       // ceil(NBOX/256): contiguous candidates per thread

// Exact upper rounding boundary of 0.45f: fdiv_rn(i,u) > 0.45f  <=>  i > M_IOU*u (u>0),
// evaluated exactly in double (25b x 24b product fits 53b). 0.45f mantissa is even ->
// the tie at M_IOU rounds DOWN to 0.45f, so strict > is the exact predicate.
// (Validated bit-exact: round-9 bench absmax 0.0.)
#define M_IOU   0.45000000298023223876953125

typedef unsigned long long u64;
typedef unsigned int       u32;

// monotone float->uint transform: ascending uint order == ascending float order
__device__ __forceinline__ u32 forder(float f) {
  u32 u = __float_as_uint(f);
  return u ^ ((u >> 31) ? 0xFFFFFFFFu : 0x80000000u);
}

// ---------------- bitonic helpers (LDS, power-of-2 NN, T threads) ----------------
template<int NN, int T>
__device__ void bsort(u64* s, int tid, bool asc) {
  for (int k = 2; k <= NN; k <<= 1) {
    for (int j = k >> 1; j > 0; j >>= 1) {
      __syncthreads();
      for (int i = tid; i < NN; i += T) {
        int p = i ^ j;
        if (p > i) {
          u64 a = s[i], b = s[p];
          bool up = (((i & k) == 0) == asc);
          if (up ? (a > b) : (a < b)) { s[i] = b; s[p] = a; }
        }
      }
    }
  }
  __syncthreads();
}

template<int NN, int T>
__device__ void bmerge_asc(u64* s, int tid) {
  for (int j = NN >> 1; j > 0; j >>= 1) {
    __syncthreads();
    for (int i = tid; i < NN; i += T) {
      int p = i ^ j;
      if (p > i) {
        u64 a = s[i], b = s[p];
        if (a > b) { s[i] = b; s[p] = a; }
      }
    }
  }
  __syncthreads();
}

// ---------------- kernel A: decode boxes + transpose scores ----------------
__global__ __launch_bounds__(256) void decode_transpose(
    const float* __restrict__ y, float4* __restrict__ boxes, float* __restrict__ scoresT) {
  __shared__ float tile[64 * NCH];
  int b  = blockIdx.x;
  int t0 = blockIdx.y * 64;
  int nn = NBOX - t0; if (nn > 64) nn = 64;
  const float* src = y + ((size_t)b * NBOX + t0) * NCH;
  int tid = threadIdx.x;
  for (int i = tid; i < nn * NCH; i += 256) tile[i] = src[i];
  __syncthreads();
  if (tid < nn) {
    const float* yy = &tile[tid * NCH];
    float aw = yy[87], ah = yy[88];
    float cx = __fadd_rn(__fmul_rn(__fmul_rn(yy[81], yy[89]), aw), yy[85]);
    float cy = __fadd_rn(__fmul_rn(__fmul_rn(yy[82], yy[90]), ah), yy[86]);
    float w  = __fmul_rn(expf(__fmul_rn(yy[83], yy[91])), aw);
    float h  = __fmul_rn(expf(__fmul_rn(yy[84], yy[92])), ah);
    float4 bx;
    bx.x = __fmul_rn(__fsub_rn(cx, __fmul_rn(0.5f, w)), 512.0f);
    bx.y = __fmul_rn(__fsub_rn(cy, __fmul_rn(0.5f, h)), 512.0f);
    bx.z = __fmul_rn(__fadd_rn(cx, __fmul_rn(0.5f, w)), 512.0f);
    bx.w = __fmul_rn(__fadd_rn(cy, __fmul_rn(0.5f, h)), 512.0f);
    boxes[(size_t)b * NBOX + t0 + tid] = bx;
  }
  for (int e = tid; e < NCLS * 64; e += 256) {
    int c = e >> 6, ln = e & 63;
    if (ln < nn)
      scoresT[((size_t)b * NCLS + c) * NBOX + t0 + ln] = tile[ln * NCH + 1 + c];
  }
}

// ---------------- kernel B: exact stable top-512 per (b,c) via radix-select ----
__global__ __launch_bounds__(256) void select_top512(
    const float* __restrict__ scoresT, u64* __restrict__ selkeys) {
  __shared__ u32 hist[256];
  __shared__ u64 cand[1024];
  __shared__ u32 bcast[4];   // [0]=boundary bin, [1]=cumBefore, [2]=compaction counter
  int bc  = blockIdx.x;
  int t   = threadIdx.x;
  const float* sc = scoresT + (size_t)bc * NBOX;
  int base = t * NPT;
  int cnt  = NBOX - base; cnt = cnt < 0 ? 0 : (cnt > NPT ? NPT : cnt);

  u32 khi[NPT];
  #pragma unroll
  for (int k = 0; k < NPT; ++k) {
    float s = (k < cnt) ? sc[base + k] : 0.0f;
    u32 f = forder(s);
    khi[k] = ((k < cnt) && (s > CONF)) ? ~f : 0xFFFFFFFFu;
  }

  u32 prefix = 0, cntLess = 0, cntTie = 0;
  int shift = 24, p;
  for (p = 0; p < 4; ++p) {
    shift = 24 - 8 * p;
    __syncthreads();
    hist[t] = 0;
    __syncthreads();
    #pragma unroll
    for (int k = 0; k < NPT; ++k) {
      u32 x = khi[k];
      bool match = (p == 0) || ((x >> (shift + 8)) == prefix);
      if (match) atomicAdd(&hist[(x >> shift) & 0xFFu], 1u);
    }
    __syncthreads();
    if (t < 64) {
      u32 h0 = hist[4*t], h1 = hist[4*t+1], h2 = hist[4*t+2], h3 = hist[4*t+3];
      u32 lsum = h0 + h1 + h2 + h3;
      u32 scn = lsum;
      #pragma unroll
      for (int d = 1; d < 64; d <<= 1) {
        u32 v = __shfl_up(scn, d, 64);
        if (t >= d) scn += v;
      }
      u32 before = scn - lsum;
      u32 need = 512u - cntLess;
      u32 c0 = before + h0, c1 = c0 + h1, c2 = c1 + h2, c3 = c2 + h3;
      int bin = -1; u32 cb = 0;
      if (before < need) {
        if      (c0 >= need) { bin = 4*t;     cb = before; }
        else if (c1 >= need) { bin = 4*t + 1; cb = c0; }
        else if (c2 >= need) { bin = 4*t + 2; cb = c1; }
        else if (c3 >= need) { bin = 4*t + 3; cb = c2; }
      }
      if (bin >= 0) { bcast[0] = (u32)bin; bcast[1] = cb; }
    }
    __syncthreads();
    u32 bin = bcast[0];
    prefix  = (prefix << 8) | bin;
    cntLess += bcast[1];
    cntTie  = hist[bin];
    if (cntLess + cntTie <= 1024u) break;
  }

  if (p < 4) {
    __syncthreads();
    if (t == 0) bcast[2] = 0;
    __syncthreads();
    #pragma unroll
    for (int k = 0; k < NPT; ++k) {
      u32 x = khi[k];
      if ((x >> shift) <= prefix) {
        u32 pos = atomicAdd(&bcast[2], 1u);
        cand[pos] = ((u64)x << 32) | (u32)(base + k);
      }
    }
    __syncthreads();
    u32 m = bcast[2];
    for (int i = t; i < 1024; i += 256) if (i >= (int)m) cand[i] = ~0ULL;
    bsort<1024, 256>(cand, t, true);
    for (int i = t; i < KSEL; i += 256) selkeys[(size_t)bc * KSEL + i] = cand[i];
  } else {
    u32 V = prefix;
    __syncthreads();
    if (t == 0) bcast[2] = 0;
    __syncthreads();
    #pragma unroll
    for (int k = 0; k < NPT; ++k) {
      u32 x = khi[k];
      if (x < V) {
        u32 pos = atomicAdd(&bcast[2], 1u);
        cand[pos] = ((u64)x << 32) | (u32)(base + k);
      }
    }
    __syncthreads();
    u32 m = bcast[2];
    for (int i = t; i < 512; i += 256) if (i >= (int)m) cand[i] = ~0ULL;
    bsort<512, 256>(cand, t, true);
    for (int i = t; i < (int)m; i += 256) selkeys[(size_t)bc * KSEL + i] = cand[i];
    u32 myeq = 0;
    #pragma unroll
    for (int k = 0; k < NPT; ++k) if (khi[k] == V) myeq++;
    __syncthreads();
    hist[t] = myeq;
    __syncthreads();
    for (int d = 1; d < 256; d <<= 1) {
      u32 v = hist[t];
      u32 w = (t >= d) ? hist[t - d] : 0u;
      __syncthreads();
      hist[t] = v + w;
      __syncthreads();
    }
    u32 r = hist[t] - myeq;
    u32 needEq = 512u - m;
    #pragma unroll
    for (int k = 0; k < NPT; ++k) {
      if (khi[k] == V) {
        if (r < needEq)
          selkeys[(size_t)bc * KSEL + m + r] = ((u64)V << 32) | (u32)(base + k);
        r++;
      }
    }
  }
}

// ---------------- kernel C: bitmask-matrix greedy NMS per (b,c) ----------------
// 256 threads (4 waves). Per 64-candidate tile T:
//  (a) matrix phase (all 4 waves): column masks cmat[jl][w] = bits "candidate i
//      (row word w) suppresses candidate j=T*64+jl" via the exact IOU predicate.
//  (b) scan phase (wave 0): lane jl holds its column mask in 8 u64 REGISTERS
//      (statically indexed via full tile unroll). Suppression-by-earlier-kept is
//      OR(cm[w] & keptmask[w]) — pure VALU. Intra-tile greedy = ffs + register
//      bit test + ballot (~40cy per kept, no LDS/shfl in the chain).
// Early exit at 200 kept skips later tiles' matrix work.
__global__ __launch_bounds__(256) void nms(
    const u64* __restrict__ selkeys, const float4* __restrict__ boxes,
    float* __restrict__ rows, u64* __restrict__ keys) {
  __shared__ float4 sbox[KSEL];
  __shared__ float  sarea[KSEL];
  __shared__ float  sscore[KSEL];
  __shared__ unsigned char svalid[KSEL];
  __shared__ u64   cmat[64][8];
  __shared__ short skidx[RPC];
  __shared__ int   s_gcount;
  int bc = blockIdx.x;
  int b = bc / NCLS, c = bc % NCLS;
  int tid = threadIdx.x;

  // load + decode 512 candidates into LDS
  for (int i = tid; i < KSEL; i += 256) {
    u64 k  = selkeys[(size_t)bc * KSEL + i];
    u32 khi = (u32)(k >> 32);
    u32 idx = (u32)k;
    bool val = (khi != 0xFFFFFFFFu);
    u32 x = ~khi;                                   // recover score bits from key
    u32 bits = (x & 0x80000000u) ? (x ^ 0x80000000u) : ~x;
    sscore[i] = __uint_as_float(bits);
    svalid[i] = val ? 1 : 0;
    float4 bx = make_float4(0.f, 0.f, 0.f, 0.f);
    if (val && idx < NBOX) bx = boxes[(size_t)b * NBOX + idx];
    sbox[i] = bx;
    sarea[i] = __fmul_rn(__fsub_rn(bx.z, bx.x), __fsub_rn(bx.w, bx.y));
  }
  if (tid == 0) s_gcount = 0;
  __syncthreads();

  u64 keptm[8] = {0,0,0,0,0,0,0,0};   // scan-wave state (uniform across wave 0)

  #pragma unroll
  for (int T = 0; T < 8; ++T) {
    bool active = (s_gcount < RPC);   // uniform (read after barrier)
    if (active) {
      // (a) matrix: tasks = 64 columns x (T+1) row-words
      for (int task = tid; task < 64 * (T + 1); task += 256) {
        int jl = task & 63, wi = task >> 6;
        int j = T * 64 + jl;
        float4 bj = sbox[j];
        float ab = sarea[j];
        u64 m = 0;
        for (int ii = 0; ii < 64; ++ii) {
          int i = wi * 64 + ii;
          float4 bi = sbox[i];                       // broadcast within wave
          float aa = sarea[i];                       // keeper = area_a operand
          float ix1 = fmaxf(bi.x, bj.x);
          float iy1 = fmaxf(bi.y, bj.y);
          float ix2 = fminf(bi.z, bj.z);
          float iy2 = fminf(bi.w, bj.w);
          float iw = fmaxf(__fsub_rn(ix2, ix1), 0.f);
          float ih = fmaxf(__fsub_rn(iy2, iy1), 0.f);
          float inter = __fmul_rn(iw, ih);
          float un = __fsub_rn(__fadd_rn(aa, ab), inter);
          bool s = (un > 0.f) && ((double)inter > M_IOU * (double)un);
          m |= ((u64)(s ? 1u : 0u)) << ii;
        }
        cmat[jl][wi] = m;
      }
    }
    __syncthreads();
    if (active && tid < 64) {
      int lane = tid;
      // column mask -> registers (static w index after unroll; w>T zeroed)
      u64 cm[8];
      #pragma unroll
      for (int w = 0; w < 8; ++w) cm[w] = (w <= T) ? cmat[lane][w] : 0ull;
      int count = s_gcount;
      u64 hit = 0;
      #pragma unroll
      for (int w = 0; w < 8; ++w) hit |= cm[w] & keptm[w];
      bool valb = (svalid[T * 64 + lane] != 0);
      u64 alive = __ballot(valb && (hit == 0ull));
      while (alive != 0ull && count < RPC) {
        int i = __ffsll(alive) - 1;                 // lowest-ranked alive = keeper
        if (lane == i) skidx[count] = (short)(T * 64 + i);
        keptm[T] |= (1ull << i);                    // static index under unroll
        alive &= ~(1ull << i);
        count++;
        if (count >= RPC) break;
        bool ks = ((cm[T] >> i) & 1ull) != 0ull;    // register bit: i suppresses me?
        alive &= ~__ballot(ks);
      }
      if (lane == 0) s_gcount = count;
    }
    __syncthreads();
  }

  // emit rows (kept order == score desc) + keys with flat index c*400+r
  int count = s_gcount;
  for (int r = tid; r < RPC; r += 256) {
    float* row = rows + ((size_t)bc * RPC + r) * 6;
    u64 k;
    if (r < count) {
      int i = skidx[r];
      float s = sscore[i];
      float4 bx = sbox[i];
      row[0] = (float)(c + 1); row[1] = s;
      row[2] = bx.x; row[3] = bx.y; row[4] = bx.z; row[5] = bx.w;
      k = ((u64)(~forder(s)) << 32) | (u32)(c * NMSMAX + r);
    } else {
      row[0] = 0.f; row[1] = 0.f; row[2] = 0.f; row[3] = 0.f; row[4] = 0.f; row[5] = 0.f;
      k = ((u64)0x7FFFFFFFu << 32) | (u32)(c * NMSMAX + r);  // zero-row key (score 0)
    }
    keys[(size_t)bc * RPC + r] = k;
  }
}

// ---------------- kernel D1: per (b, 8-class group) top-256 ----------------
__global__ __launch_bounds__(256) void topk_l1(
    const u64* __restrict__ keys, u64* __restrict__ out1) {
  __shared__ u64 buf[256], chk[256];
  int b = blockIdx.x, g = blockIdx.y;
  const u64* kb = keys + (size_t)b * (NCLS * RPC) + (size_t)g * (8 * RPC);
  int tid = threadIdx.x;
  buf[tid] = kb[tid];
  bsort<256, 256>(buf, tid, true);
  for (int c0 = 256; c0 < 1792; c0 += 256) {
    int n = c0 + tid;
    chk[tid] = (n < 8 * RPC) ? kb[n] : ~0ULL;
    bsort<256, 256>(chk, tid, false);
    u64 a = buf[tid], bb = chk[tid];
    buf[tid] = (a < bb) ? a : bb;
    bmerge_asc<256, 256>(buf, tid);
  }
  out1[((size_t)b * 10 + g) * 256 + tid] = buf[tid];
}

// ---------------- kernel D2: per batch top-200 + gather ----------------
__global__ __launch_bounds__(256) void topk_l2(
    const u64* __restrict__ out1, const float* __restrict__ rows, float* __restrict__ out) {
  __shared__ u64 buf[256], chk[256];
  int b = blockIdx.x;
  const u64* kb = out1 + (size_t)b * 2560;
  int tid = threadIdx.x;
  buf[tid] = kb[tid];
  bsort<256, 256>(buf, tid, true);
  for (int c0 = 256; c0 < 2560; c0 += 256) {
    chk[tid] = kb[c0 + tid];
    bsort<256, 256>(chk, tid, false);
    u64 a = buf[tid], bb = chk[tid];
    buf[tid] = (a < bb) ? a : bb;
    bmerge_asc<256, 256>(buf, tid);
  }
  if (tid < TOPK) {
    u64 k = buf[tid];
    u32 f = (u32)k;
    float* o = out + ((size_t)b * TOPK + tid) * 6;
    if (f == 0xFFFFFFFFu) {
      o[0]=0.f; o[1]=0.f; o[2]=0.f; o[3]=0.f; o[4]=0.f; o[5]=0.f;
    } else {
      u32 c = f / NMSMAX;
      u32 r = f % NMSMAX;
      const float* row = rows + (((size_t)b * NCLS + c) * RPC + r) * 6;
      o[0]=row[0]; o[1]=row[1]; o[2]=row[2]; o[3]=row[3]; o[4]=row[4]; o[5]=row[5];
    }
  }
}

extern "C" void kernel_launch(void* const* d_in, const int* in_sizes, int n_in,
                              void* d_out, int out_size, void* d_ws, size_t ws_size,
                              hipStream_t stream) {
  (void)in_sizes; (void)n_in; (void)out_size; (void)ws_size;
  const float* y = (const float*)d_in[0];
  float* out = (float*)d_out;
  char* ws = (char*)d_ws;

  constexpr size_t OFF_BOXES   = 0;
  constexpr size_t SZ_BOXES    = (size_t)BATCH * NBOX * 4 * 4;
  constexpr size_t OFF_SCORES  = OFF_BOXES + SZ_BOXES;
  constexpr size_t SZ_SCORES   = (size_t)BATCH * NCLS * NBOX * 4;
  constexpr size_t OFF_SELKEYS = OFF_SCORES + SZ_SCORES;
  constexpr size_t SZ_SELKEYS  = (size_t)BATCH * NCLS * KSEL * 8;
  constexpr size_t OFF_ROWS    = OFF_SELKEYS + SZ_SELKEYS;
  constexpr size_t SZ_ROWS     = (size_t)BATCH * NCLS * RPC * 6 * 4;
  constexpr size_t OFF_KEYS    = OFF_ROWS + SZ_ROWS;
  constexpr size_t SZ_KEYS     = (size_t)BATCH * NCLS * RPC * 8;
  constexpr size_t OFF_OUT1    = OFF_KEYS + SZ_KEYS;

  float4* boxes  = (float4*)(ws + OFF_BOXES);
  float* scoresT = (float*)(ws + OFF_SCORES);
  u64* selkeys   = (u64*)(ws + OFF_SELKEYS);
  float* rows    = (float*)(ws + OFF_ROWS);
  u64* keys      = (u64*)(ws + OFF_KEYS);
  u64* out1      = (u64*)(ws + OFF_OUT1);

  dim3 gA(BATCH, (NBOX + 63) / 64);
  decode_transpose<<<gA, 256, 0, stream>>>(y, boxes, scoresT);
  select_top512<<<BATCH * NCLS, 256, 0, stream>>>(scoresT, selkeys);
  nms<<<BATCH * NCLS, 256, 0, stream>>>(selkeys, boxes, rows, keys);
  dim3 gD1(BATCH, 10);
  topk_l1<<<gD1, 256, 0, stream>>>(keys, out1);
  topk_l2<<<BATCH, 256, 0, stream>>>(out1, rows, out);
}

// Round 12
// 613.531 us; speedup vs baseline: 1.1278x; 1.1278x over previous
//
#include <hip/hip_runtime.h>
#include <stdint.h>

// DecodeDetections (SSD): decode + per-class top-512 + greedy NMS + per-batch top-200.
// B=32, N=8732, C=80 foreground classes, K=512 candidates, NMS cap 400, out top-200.

#define BATCH   32
#define NBOX    8732
#define NCH     93
#define NCLS    80
#define KSEL    512
#define NMSMAX  400
#define RPC     200      // rows materialized per class (top-200 of batch can't reach deeper;
                         // NMS may stop at 200 kept: row r>=200 has >=200 same-class rows above it)
#define TOPK    200
#define CONF    0.01f
#define IOU_T   0.45f
#define NPT     35       // ceil(NBOX/256): contiguous candidates per thread

// Exact upper rounding boundary of 0.45f: fdiv_rn(i,u) > 0.45f  <=>  i > M_IOU*u (u>0),
// evaluated exactly in double (25b x 24b product fits 53b). 0.45f mantissa is even ->
// the tie at M_IOU rounds DOWN to 0.45f, so strict > is the exact predicate.
// (Validated bit-exact: round-9/10 bench absmax 0.0.)
#define M_IOU   0.45000000298023223876953125

typedef unsigned long long u64;
typedef unsigned int       u32;

// monotone float->uint transform: ascending uint order == ascending float order
__device__ __forceinline__ u32 forder(float f) {
  u32 u = __float_as_uint(f);
  return u ^ ((u >> 31) ? 0xFFFFFFFFu : 0x80000000u);
}

// exact IOU>0.45 predicate (keeper box first: aa = keeper area)
__device__ __forceinline__ bool iou_gt(
    float kx, float ky, float kz, float kw, float aa,
    float bx, float by, float bz, float bw, float ab) {
  float ix1 = fmaxf(kx, bx);
  float iy1 = fmaxf(ky, by);
  float ix2 = fminf(kz, bz);
  float iy2 = fminf(kw, bw);
  float iw = fmaxf(__fsub_rn(ix2, ix1), 0.f);
  float ih = fmaxf(__fsub_rn(iy2, iy1), 0.f);
  float inter = __fmul_rn(iw, ih);
  float un = __fsub_rn(__fadd_rn(aa, ab), inter);
  return (un > 0.f) && ((double)inter > M_IOU * (double)un);
}

// ---------------- bitonic helpers (LDS, power-of-2 NN, T threads) ----------------
template<int NN, int T>
__device__ void bsort(u64* s, int tid, bool asc) {
  for (int k = 2; k <= NN; k <<= 1) {
    for (int j = k >> 1; j > 0; j >>= 1) {
      __syncthreads();
      for (int i = tid; i < NN; i += T) {
        int p = i ^ j;
        if (p > i) {
          u64 a = s[i], b = s[p];
          bool up = (((i & k) == 0) == asc);
          if (up ? (a > b) : (a < b)) { s[i] = b; s[p] = a; }
        }
      }
    }
  }
  __syncthreads();
}

template<int NN, int T>
__device__ void bmerge_asc(u64* s, int tid) {
  for (int j = NN >> 1; j > 0; j >>= 1) {
    __syncthreads();
    for (int i = tid; i < NN; i += T) {
      int p = i ^ j;
      if (p > i) {
        u64 a = s[i], b = s[p];
        if (a > b) { s[i] = b; s[p] = a; }
      }
    }
  }
  __syncthreads();
}

// ---------------- kernel A: decode boxes + transpose scores ----------------
__global__ __launch_bounds__(256) void decode_transpose(
    const float* __restrict__ y, float4* __restrict__ boxes, float* __restrict__ scoresT) {
  __shared__ float tile[64 * NCH];
  int b  = blockIdx.x;
  int t0 = blockIdx.y * 64;
  int nn = NBOX - t0; if (nn > 64) nn = 64;
  const float* src = y + ((size_t)b * NBOX + t0) * NCH;
  int tid = threadIdx.x;
  for (int i = tid; i < nn * NCH; i += 256) tile[i] = src[i];
  __syncthreads();
  if (tid < nn) {
    const float* yy = &tile[tid * NCH];
    float aw = yy[87], ah = yy[88];
    float cx = __fadd_rn(__fmul_rn(__fmul_rn(yy[81], yy[89]), aw), yy[85]);
    float cy = __fadd_rn(__fmul_rn(__fmul_rn(yy[82], yy[90]), ah), yy[86]);
    float w  = __fmul_rn(expf(__fmul_rn(yy[83], yy[91])), aw);
    float h  = __fmul_rn(expf(__fmul_rn(yy[84], yy[92])), ah);
    float4 bx;
    bx.x = __fmul_rn(__fsub_rn(cx, __fmul_rn(0.5f, w)), 512.0f);
    bx.y = __fmul_rn(__fsub_rn(cy, __fmul_rn(0.5f, h)), 512.0f);
    bx.z = __fmul_rn(__fadd_rn(cx, __fmul_rn(0.5f, w)), 512.0f);
    bx.w = __fmul_rn(__fadd_rn(cy, __fmul_rn(0.5f, h)), 512.0f);
    boxes[(size_t)b * NBOX + t0 + tid] = bx;
  }
  for (int e = tid; e < NCLS * 64; e += 256) {
    int c = e >> 6, ln = e & 63;
    if (ln < nn)
      scoresT[((size_t)b * NCLS + c) * NBOX + t0 + ln] = tile[ln * NCH + 1 + c];
  }
}

// ---------------- kernel B: exact stable top-512 per (b,c) via radix-select ----
__global__ __launch_bounds__(256) void select_top512(
    const float* __restrict__ scoresT, u64* __restrict__ selkeys) {
  __shared__ u32 hist[256];
  __shared__ u64 cand[1024];
  __shared__ u32 bcast[4];   // [0]=boundary bin, [1]=cumBefore, [2]=compaction counter
  int bc  = blockIdx.x;
  int t   = threadIdx.x;
  const float* sc = scoresT + (size_t)bc * NBOX;
  int base = t * NPT;
  int cnt  = NBOX - base; cnt = cnt < 0 ? 0 : (cnt > NPT ? NPT : cnt);

  u32 khi[NPT];
  #pragma unroll
  for (int k = 0; k < NPT; ++k) {
    float s = (k < cnt) ? sc[base + k] : 0.0f;
    u32 f = forder(s);
    khi[k] = ((k < cnt) && (s > CONF)) ? ~f : 0xFFFFFFFFu;
  }

  u32 prefix = 0, cntLess = 0, cntTie = 0;
  int shift = 24, p;
  for (p = 0; p < 4; ++p) {
    shift = 24 - 8 * p;
    __syncthreads();
    hist[t] = 0;
    __syncthreads();
    #pragma unroll
    for (int k = 0; k < NPT; ++k) {
      u32 x = khi[k];
      bool match = (p == 0) || ((x >> (shift + 8)) == prefix);
      if (match) atomicAdd(&hist[(x >> shift) & 0xFFu], 1u);
    }
    __syncthreads();
    if (t < 64) {
      u32 h0 = hist[4*t], h1 = hist[4*t+1], h2 = hist[4*t+2], h3 = hist[4*t+3];
      u32 lsum = h0 + h1 + h2 + h3;
      u32 scn = lsum;
      #pragma unroll
      for (int d = 1; d < 64; d <<= 1) {
        u32 v = __shfl_up(scn, d, 64);
        if (t >= d) scn += v;
      }
      u32 before = scn - lsum;
      u32 need = 512u - cntLess;
      u32 c0 = before + h0, c1 = c0 + h1, c2 = c1 + h2, c3 = c2 + h3;
      int bin = -1; u32 cb = 0;
      if (before < need) {
        if      (c0 >= need) { bin = 4*t;     cb = before; }
        else if (c1 >= need) { bin = 4*t + 1; cb = c0; }
        else if (c2 >= need) { bin = 4*t + 2; cb = c1; }
        else if (c3 >= need) { bin = 4*t + 3; cb = c2; }
      }
      if (bin >= 0) { bcast[0] = (u32)bin; bcast[1] = cb; }
    }
    __syncthreads();
    u32 bin = bcast[0];
    prefix  = (prefix << 8) | bin;
    cntLess += bcast[1];
    cntTie  = hist[bin];
    if (cntLess + cntTie <= 1024u) break;
  }

  if (p < 4) {
    __syncthreads();
    if (t == 0) bcast[2] = 0;
    __syncthreads();
    #pragma unroll
    for (int k = 0; k < NPT; ++k) {
      u32 x = khi[k];
      if ((x >> shift) <= prefix) {
        u32 pos = atomicAdd(&bcast[2], 1u);
        cand[pos] = ((u64)x << 32) | (u32)(base + k);
      }
    }
    __syncthreads();
    u32 m = bcast[2];
    for (int i = t; i < 1024; i += 256) if (i >= (int)m) cand[i] = ~0ULL;
    bsort<1024, 256>(cand, t, true);
    for (int i = t; i < KSEL; i += 256) selkeys[(size_t)bc * KSEL + i] = cand[i];
  } else {
    u32 V = prefix;
    __syncthreads();
    if (t == 0) bcast[2] = 0;
    __syncthreads();
    #pragma unroll
    for (int k = 0; k < NPT; ++k) {
      u32 x = khi[k];
      if (x < V) {
        u32 pos = atomicAdd(&bcast[2], 1u);
        cand[pos] = ((u64)x << 32) | (u32)(base + k);
      }
    }
    __syncthreads();
    u32 m = bcast[2];
    for (int i = t; i < 512; i += 256) if (i >= (int)m) cand[i] = ~0ULL;
    bsort<512, 256>(cand, t, true);
    for (int i = t; i < (int)m; i += 256) selkeys[(size_t)bc * KSEL + i] = cand[i];
    u32 myeq = 0;
    #pragma unroll
    for (int k = 0; k < NPT; ++k) if (khi[k] == V) myeq++;
    __syncthreads();
    hist[t] = myeq;
    __syncthreads();
    for (int d = 1; d < 256; d <<= 1) {
      u32 v = hist[t];
      u32 w = (t >= d) ? hist[t - d] : 0u;
      __syncthreads();
      hist[t] = v + w;
      __syncthreads();
    }
    u32 r = hist[t] - myeq;
    u32 needEq = 512u - m;
    #pragma unroll
    for (int k = 0; k < NPT; ++k) {
      if (khi[k] == V) {
        if (r < needEq)
          selkeys[(size_t)bc * KSEL + m + r] = ((u64)V << 32) | (u32)(base + k);
        r++;
      }
    }
  }
}

// ---------------- kernel C: kept-list bitmask greedy NMS per (b,c) -------------
// 256 threads (4 waves), SoA LDS (conflict-free). Per 64-candidate tile T:
//  A) 4 waves chunk the KEPT list: suppressed-by-kept per candidate via ballot
//     (kept reads are wave-uniform -> LDS broadcast).
//  B) intra-tile 64x64 matrix, 16 rows/wave -> scmat[64][5] (padded, 2-way free).
//  C) wave-0 scan: register bitmask greedy (ffs + bit test + ballot), appends to
//     the kept index list. Early exit at 200 kept.
// Work ~= 32K intra IOU + sum_T 64*count_T (only what greedy consumes).
__global__ __launch_bounds__(256) void nms(
    const u64* __restrict__ selkeys, const float4* __restrict__ boxes,
    float* __restrict__ rows, u64* __restrict__ keys) {
  __shared__ float sx[KSEL], sy[KSEL], sz[KSEL], sw_[KSEL], sa[KSEL], ss[KSEL];
  __shared__ unsigned char svalid[KSEL];
  __shared__ short skidx[RPC];
  __shared__ int   s_gcount;
  __shared__ u64   ssup[4];
  __shared__ u32   scmat[64][5];   // [col][rowchunk], padded to 5 (bank-spread)
  int bc = blockIdx.x;
  int b = bc / NCLS, c = bc % NCLS;
  int tid = threadIdx.x;

  // load + decode 512 candidates into SoA LDS
  for (int i = tid; i < KSEL; i += 256) {
    u64 k  = selkeys[(size_t)bc * KSEL + i];
    u32 khi = (u32)(k >> 32);
    u32 idx = (u32)k;
    bool val = (khi != 0xFFFFFFFFu);
    u32 x = ~khi;                                   // recover score bits from key
    u32 bits = (x & 0x80000000u) ? (x ^ 0x80000000u) : ~x;
    ss[i] = __uint_as_float(bits);
    svalid[i] = val ? 1 : 0;
    float4 bx = make_float4(0.f, 0.f, 0.f, 0.f);
    if (val && idx < NBOX) bx = boxes[(size_t)b * NBOX + idx];
    sx[i] = bx.x; sy[i] = bx.y; sz[i] = bx.z; sw_[i] = bx.w;
    sa[i] = __fmul_rn(__fsub_rn(bx.z, bx.x), __fsub_rn(bx.w, bx.y));
  }
  if (tid == 0) s_gcount = 0;
  __syncthreads();

  int jl = tid & 63, wv = tid >> 6;
  for (int T = 0; T < 8; ++T) {
    int count = s_gcount;            // uniform (read after barrier)
    if (count >= RPC) break;         // uniform branch
    int j = T * 64 + jl;
    float bjx = sx[j], bjy = sy[j], bjz = sz[j], bjw = sw_[j], ab = sa[j];

    // A) vs kept list, chunked across the 4 waves (reads broadcast)
    bool supA = false;
    for (int r = wv; r < count; r += 4) {
      int ki = skidx[r];
      if (iou_gt(sx[ki], sy[ki], sz[ki], sw_[ki], sa[ki], bjx, bjy, bjz, bjw, ab))
        supA = true;
    }
    u64 bwm = __ballot(supA);
    if (jl == 0) ssup[wv] = bwm;

    // B) intra-tile rows [wv*16, wv*16+16) (keeper reads uniform -> broadcast)
    u32 mchunk = 0;
    #pragma unroll
    for (int k = 0; k < 16; ++k) {
      int i = T * 64 + wv * 16 + k;
      bool s = iou_gt(sx[i], sy[i], sz[i], sw_[i], sa[i], bjx, bjy, bjz, bjw, ab);
      mchunk |= (s ? 1u : 0u) << k;
    }
    scmat[jl][wv] = mchunk;
    __syncthreads();

    // C) wave-0 register-bitmask greedy scan
    if (tid < 64) {
      int lane = tid;
      u64 cm = (u64)scmat[lane][0] | ((u64)scmat[lane][1] << 16)
             | ((u64)scmat[lane][2] << 32) | ((u64)scmat[lane][3] << 48);
      u64 supm = ssup[0] | ssup[1] | ssup[2] | ssup[3];
      bool valb = (svalid[T * 64 + lane] != 0);
      u64 alive = __ballot(valb && !((supm >> lane) & 1ull));
      int cnt = count;
      while (alive != 0ull && cnt < RPC) {
        int i = __ffsll(alive) - 1;                 // lowest-ranked alive = keeper
        if (lane == 0) skidx[cnt] = (short)(T * 64 + i);
        alive &= ~(1ull << i);
        cnt++;
        if (cnt >= RPC) break;
        bool ks = ((cm >> i) & 1ull) != 0ull;       // register bit: i suppresses me?
        alive &= ~__ballot(ks);
      }
      if (lane == 0) s_gcount = cnt;
    }
    __syncthreads();
  }

  // emit rows (kept order == score desc) + keys with flat index c*400+r
  int count = s_gcount;
  for (int r = tid; r < RPC; r += 256) {
    float* row = rows + ((size_t)bc * RPC + r) * 6;
    u64 k;
    if (r < count) {
      int i = skidx[r];
      float s = ss[i];
      row[0] = (float)(c + 1); row[1] = s;
      row[2] = sx[i]; row[3] = sy[i]; row[4] = sz[i]; row[5] = sw_[i];
      k = ((u64)(~forder(s)) << 32) | (u32)(c * NMSMAX + r);
    } else {
      row[0] = 0.f; row[1] = 0.f; row[2] = 0.f; row[3] = 0.f; row[4] = 0.f; row[5] = 0.f;
      k = ((u64)0x7FFFFFFFu << 32) | (u32)(c * NMSMAX + r);  // zero-row key (score 0)
    }
    keys[(size_t)bc * RPC + r] = k;
  }
}

// ---------------- kernel D1: per (b, 8-class group) top-256 ----------------
__global__ __launch_bounds__(256) void topk_l1(
    const u64* __restrict__ keys, u64* __restrict__ out1) {
  __shared__ u64 buf[256], chk[256];
  int b = blockIdx.x, g = blockIdx.y;
  const u64* kb = keys + (size_t)b * (NCLS * RPC) + (size_t)g * (8 * RPC);
  int tid = threadIdx.x;
  buf[tid] = kb[tid];
  bsort<256, 256>(buf, tid, true);
  for (int c0 = 256; c0 < 1792; c0 += 256) {
    int n = c0 + tid;
    chk[tid] = (n < 8 * RPC) ? kb[n] : ~0ULL;
    bsort<256, 256>(chk, tid, false);
    u64 a = buf[tid], bb = chk[tid];
    buf[tid] = (a < bb) ? a : bb;
    bmerge_asc<256, 256>(buf, tid);
  }
  out1[((size_t)b * 10 + g) * 256 + tid] = buf[tid];
}

// ---------------- kernel D2: per batch top-200 + gather ----------------
__global__ __launch_bounds__(256) void topk_l2(
    const u64* __restrict__ out1, const float* __restrict__ rows, float* __restrict__ out) {
  __shared__ u64 buf[256], chk[256];
  int b = blockIdx.x;
  const u64* kb = out1 + (size_t)b * 2560;
  int tid = threadIdx.x;
  buf[tid] = kb[tid];
  bsort<256, 256>(buf, tid, true);
  for (int c0 = 256; c0 < 2560; c0 += 256) {
    chk[tid] = kb[c0 + tid];
    bsort<256, 256>(chk, tid, false);
    u64 a = buf[tid], bb = chk[tid];
    buf[tid] = (a < bb) ? a : bb;
    bmerge_asc<256, 256>(buf, tid);
  }
  if (tid < TOPK) {
    u64 k = buf[tid];
    u32 f = (u32)k;
    float* o = out + ((size_t)b * TOPK + tid) * 6;
    if (f == 0xFFFFFFFFu) {
      o[0]=0.f; o[1]=0.f; o[2]=0.f; o[3]=0.f; o[4]=0.f; o[5]=0.f;
    } else {
      u32 c = f / NMSMAX;
      u32 r = f % NMSMAX;
      const float* row = rows + (((size_t)b * NCLS + c) * RPC + r) * 6;
      o[0]=row[0]; o[1]=row[1]; o[2]=row[2]; o[3]=row[3]; o[4]=row[4]; o[5]=row[5];
    }
  }
}

extern "C" void kernel_launch(void* const* d_in, const int* in_sizes, int n_in,
                              void* d_out, int out_size, void* d_ws, size_t ws_size,
                              hipStream_t stream) {
  (void)in_sizes; (void)n_in; (void)out_size; (void)ws_size;
  const float* y = (const float*)d_in[0];
  float* out = (float*)d_out;
  char* ws = (char*)d_ws;

  constexpr size_t OFF_BOXES   = 0;
  constexpr size_t SZ_BOXES    = (size_t)BATCH * NBOX * 4 * 4;
  constexpr size_t OFF_SCORES  = OFF_BOXES + SZ_BOXES;
  constexpr size_t SZ_SCORES   = (size_t)BATCH * NCLS * NBOX * 4;
  constexpr size_t OFF_SELKEYS = OFF_SCORES + SZ_SCORES;
  constexpr size_t SZ_SELKEYS  = (size_t)BATCH * NCLS * KSEL * 8;
  constexpr size_t OFF_ROWS    = OFF_SELKEYS + SZ_SELKEYS;
  constexpr size_t SZ_ROWS     = (size_t)BATCH * NCLS * RPC * 6 * 4;
  constexpr size_t OFF_KEYS    = OFF_ROWS + SZ_ROWS;
  constexpr size_t SZ_KEYS     = (size_t)BATCH * NCLS * RPC * 8;
  constexpr size_t OFF_OUT1    = OFF_KEYS + SZ_KEYS;

  float4* boxes  = (float4*)(ws + OFF_BOXES);
  float* scoresT = (float*)(ws + OFF_SCORES);
  u64* selkeys   = (u64*)(ws + OFF_SELKEYS);
  float* rows    = (float*)(ws + OFF_ROWS);
  u64* keys      = (u64*)(ws + OFF_KEYS);
  u64* out1      = (u64*)(ws + OFF_OUT1);

  dim3 gA(BATCH, (NBOX + 63) / 64);
  decode_transpose<<<gA, 256, 0, stream>>>(y, boxes, scoresT);
  select_top512<<<BATCH * NCLS, 256, 0, stream>>>(scoresT, selkeys);
  nms<<<BATCH * NCLS, 256, 0, stream>>>(selkeys, boxes, rows, keys);
  dim3 gD1(BATCH, 10);
  topk_l1<<<gD1, 256, 0, stream>>>(keys, out1);
  topk_l2<<<BATCH, 256, 0, stream>>>(out1, rows, out);
}